// Round 1
// baseline (3263.927 us; speedup 1.0000x reference)
//
#include <hip/hip_runtime.h>
#include <cstdint>
#include <cstddef>

// ---- problem constants (fixed by reference) ----
#define SEQ    2048
#define BATCH  2
#define NH     8
#define NKV    2
#define DH     256
#define MR     (BATCH*SEQ)          // 4096 rows
#define HID    2048
#define NGRP   (NH/NKV)             // 4

// =====================================================================
// Generic fp32 GEMM: C[M,N] = A[M,K] @ B[K,N], row-major.
// 128x128 tile, 256 threads, 8x8 per-thread microtile, K-step 16.
// Requires N%128==0, K%16==0, M%128==0 (true for all uses here).
// LDS stride 132 floats: 16B-aligned float4 reads, <=2-way bank aliasing.
// =====================================================================
__device__ __forceinline__ void gemm_body(const float* __restrict__ A,
                                          const float* __restrict__ B,
                                          float* __restrict__ C,
                                          int N, int K, int bx, int by) {
  __shared__ float As[16][132];
  __shared__ float Bs[16][132];
  const int t  = threadIdx.x;
  const int tx = t & 15, ty = t >> 4;
  const int arow = t >> 2, ak = (t & 3) << 2;     // A-stage: 64 rows x 16 k per pass (2 passes)
  const int bk = t >> 4, bc = (t & 15) << 3;      // B-stage: 16 k-rows x 128 cols

  const float* Ap0 = A + (size_t)(by * 128 + arow) * K + ak;
  const float* Ap1 = Ap0 + (size_t)64 * K;
  const float* Bp  = B + (size_t)bk * N + bx * 128 + bc;

  float acc[8][8] = {};

  for (int k0 = 0; k0 < K; k0 += 16) {
    // issue global loads early (latency hides under the barrier)
    const float4 a4l = *(const float4*)(Ap0 + k0);
    const float4 a4h = *(const float4*)(Ap1 + k0);
    const float4 b40 = *(const float4*)(Bp + (size_t)k0 * N);
    const float4 b41 = *(const float4*)(Bp + (size_t)k0 * N + 4);
    __syncthreads();                 // previous tile's LDS reads done
    // A staged transposed: As[k][m]
    As[ak + 0][arow] = a4l.x; As[ak + 1][arow] = a4l.y;
    As[ak + 2][arow] = a4l.z; As[ak + 3][arow] = a4l.w;
    As[ak + 0][64 + arow] = a4h.x; As[ak + 1][64 + arow] = a4h.y;
    As[ak + 2][64 + arow] = a4h.z; As[ak + 3][64 + arow] = a4h.w;
    *(float4*)&Bs[bk][bc]     = b40;
    *(float4*)&Bs[bk][bc + 4] = b41;
    __syncthreads();

#pragma unroll
    for (int k = 0; k < 16; ++k) {
      const float4 a0 = *(const float4*)&As[k][ty * 4];
      const float4 a1 = *(const float4*)&As[k][64 + ty * 4];
      const float4 b0 = *(const float4*)&Bs[k][tx * 4];
      const float4 b1 = *(const float4*)&Bs[k][64 + tx * 4];
      const float av[8] = {a0.x, a0.y, a0.z, a0.w, a1.x, a1.y, a1.z, a1.w};
      const float bv[8] = {b0.x, b0.y, b0.z, b0.w, b1.x, b1.y, b1.z, b1.w};
#pragma unroll
      for (int i = 0; i < 8; ++i)
#pragma unroll
        for (int j = 0; j < 8; ++j)
          acc[i][j] = fmaf(av[i], bv[j], acc[i][j]);
    }
  }

  float* Cb = C + (size_t)(by * 128) * N + bx * 128;
#pragma unroll
  for (int i = 0; i < 8; ++i) {
    const int r = (i < 4) ? (ty * 4 + i) : (64 + ty * 4 + (i - 4));
    const float4 c0 = make_float4(acc[i][0], acc[i][1], acc[i][2], acc[i][3]);
    const float4 c1 = make_float4(acc[i][4], acc[i][5], acc[i][6], acc[i][7]);
    *(float4*)(Cb + (size_t)r * N + tx * 4)      = c0;
    *(float4*)(Cb + (size_t)r * N + 64 + tx * 4) = c1;
  }
}

__global__ __launch_bounds__(256) void gemm_f32(const float* __restrict__ A,
                                                const float* __restrict__ B,
                                                float* __restrict__ C,
                                                int N, int K) {
  gemm_body(A, B, C, N, K, blockIdx.x, blockIdx.y);
}

// K and V projections fused into one launch (each alone is a 128-block grid).
__global__ __launch_bounds__(256) void gemm_kv_f32(const float* __restrict__ A,
                                                   const float* __restrict__ Bk,
                                                   const float* __restrict__ Bv,
                                                   float* __restrict__ Ck,
                                                   float* __restrict__ Cv,
                                                   int K) {
  if (blockIdx.x < 4) gemm_body(A, Bk, Ck, 512, K, blockIdx.x, blockIdx.y);
  else                gemm_body(A, Bv, Cv, 512, K, blockIdx.x - 4, blockIdx.y);
}

// =====================================================================
// Fused RMSNorm (+optional scale) + RoPE, in-place, one 256-elem row/block.
// Row id space: [0,32768) = Q rows (b,s,h), [32768,40960) = K rows,
// [40960,49152) = V rows (norm only, no scale, no rope).
// =====================================================================
__global__ __launch_bounds__(256) void norm_rope(float* __restrict__ Q,
                                                 float* __restrict__ Kb,
                                                 float* __restrict__ Vb,
                                                 const float* __restrict__ q_scale,
                                                 const float* __restrict__ k_scale) {
  const int idx = blockIdx.x;
  const int t = threadIdx.x;
  float* base;
  const float* scale = nullptr;
  bool rope = false;
  int s = 0;
  if (idx < 32768) {              // Q: idx = (b*S+s)*8 + h
    base = Q + (size_t)idx * DH; scale = q_scale; rope = true;
    s = (idx >> 3) & (SEQ - 1);
  } else if (idx < 40960) {       // K: i = (b*S+s)*2 + kh
    const int i = idx - 32768;
    base = Kb + (size_t)i * DH; scale = k_scale; rope = true;
    s = (i >> 1) & (SEQ - 1);
  } else {                        // V: norm only
    const int i = idx - 40960;
    base = Vb + (size_t)i * DH;
  }

  const float x = base[t];
  float ss = x * x;
#pragma unroll
  for (int off = 32; off; off >>= 1) ss += __shfl_xor(ss, off);
  __shared__ float red[4];
  if ((t & 63) == 0) red[t >> 6] = ss;
  __syncthreads();
  const float tot = red[0] + red[1] + red[2] + red[3];
  const float inv = rsqrtf(tot * (1.0f / 256.0f) + 1e-6f);
  float xn = x * inv;
  if (scale) xn *= scale[t];

  if (rope) {
    __shared__ float rowbuf[256];
    rowbuf[t] = xn;
    __syncthreads();
    const int f = t & 127;
    // inv_freq = 10000^(-f/128) = exp(-f * ln(10000)/128)
    const float invf = expf(-0.07195578415606391f * (float)f);
    const float ang = (float)s * invf;
    float sn, cs;
    sincosf(ang, &sn, &cs);
    const float other = rowbuf[t ^ 128];
    const float out = (t < 128) ? (xn * cs - other * sn)
                                : (xn * cs + other * sn);
    base[t] = out;
  } else {
    base[t] = xn;
  }
}

// =====================================================================
// fp32 flash attention, causal, GQA (head h reads kv head h>>2).
// Block = (q-tile of 32 rows, h, b), 256 threads.
// K and V time-share one LDS buffer; online softmax per row.
// Score mapping: thread -> col sc=t&31, rows sr+8i (sr=t>>5, i=0..3).
// PV mapping:    thread -> row pr=t>>3, cols pd+32*dd (pd=(t&7)*4, dd=0..7)
//                (d-interleave => V LDS reads hit all 32 banks).
// Output written directly to [B,S,H*D] layout for the final GEMM.
// =====================================================================
__global__ __launch_bounds__(256) void attn_f32(const float* __restrict__ Q,
                                                const float* __restrict__ K,
                                                const float* __restrict__ V,
                                                float* __restrict__ O) {
  const int qt = blockIdx.x;        // 0..63
  const int h  = blockIdx.y;        // 0..7
  const int b  = blockIdx.z;        // 0..1
  const int kh = h >> 2;
  const int t  = threadIdx.x;
  const int q0 = qt * 32;

  __shared__ float Qs[32][260];
  __shared__ float KVs[32][260];
  __shared__ float Ps[32][33];

  // ---- load Q tile (one global row per wave pass) ----
  const float* Qbase = Q + ((size_t)(b * SEQ + q0) * NH + h) * DH;
#pragma unroll
  for (int it = 0; it < 8; ++it) {
    const int vi = it * 256 + t;
    const int row = vi >> 6, c4 = vi & 63;
    *(float4*)&Qs[row][c4 * 4] =
        *(const float4*)(Qbase + (size_t)row * NH * DH + c4 * 4);
  }

  const int sr = t >> 5, sc = t & 31;
  const int pr = t >> 3, pd = (t & 7) * 4;

  float m = -3.0e38f, l = 0.0f;
  float4 o[8];
#pragma unroll
  for (int dd = 0; dd < 8; ++dd) o[dd] = make_float4(0.f, 0.f, 0.f, 0.f);

  const float* Kbase = K + ((size_t)(b * SEQ) * NKV + kh) * DH;
  const float* Vbase = V + ((size_t)(b * SEQ) * NKV + kh) * DH;
  __syncthreads();

  for (int kt = 0; kt <= qt; ++kt) {
    // ---- stage K tile ----
    const float* Kt = Kbase + (size_t)kt * 32 * NKV * DH;
#pragma unroll
    for (int it = 0; it < 8; ++it) {
      const int vi = it * 256 + t;
      const int row = vi >> 6, c4 = vi & 63;
      *(float4*)&KVs[row][c4 * 4] =
          *(const float4*)(Kt + (size_t)row * NKV * DH + c4 * 4);
    }
    __syncthreads();

    // ---- scores: 4 per thread ----
    float a0 = 0.f, a1 = 0.f, a2 = 0.f, a3 = 0.f;
#pragma unroll 8
    for (int d4 = 0; d4 < 64; ++d4) {
      const float4 k4 = *(const float4*)&KVs[sc][d4 * 4];
      const float4 q0v = *(const float4*)&Qs[sr][d4 * 4];
      const float4 q1v = *(const float4*)&Qs[sr + 8][d4 * 4];
      const float4 q2v = *(const float4*)&Qs[sr + 16][d4 * 4];
      const float4 q3v = *(const float4*)&Qs[sr + 24][d4 * 4];
      a0 = fmaf(q0v.x, k4.x, fmaf(q0v.y, k4.y, fmaf(q0v.z, k4.z, fmaf(q0v.w, k4.w, a0))));
      a1 = fmaf(q1v.x, k4.x, fmaf(q1v.y, k4.y, fmaf(q1v.z, k4.z, fmaf(q1v.w, k4.w, a1))));
      a2 = fmaf(q2v.x, k4.x, fmaf(q2v.y, k4.y, fmaf(q2v.z, k4.z, fmaf(q2v.w, k4.w, a2))));
      a3 = fmaf(q3v.x, k4.x, fmaf(q3v.y, k4.y, fmaf(q3v.z, k4.z, fmaf(q3v.w, k4.w, a3))));
    }
    {
      const int j = kt * 32 + sc;
      float sv[4] = {a0, a1, a2, a3};
#pragma unroll
      for (int i = 0; i < 4; ++i) {
        const int qi = q0 + sr + 8 * i;
        float sfin = sv[i] * 0.0625f;         // 1/sqrt(256)
        if (j > qi) sfin = -1.0e30f;          // causal; exp underflows to exactly 0
        Ps[sr + 8 * i][sc] = sfin;
      }
    }
    __syncthreads();   // Ps visible; all K reads from KVs done

    // ---- stage V to registers (hide HBM latency under softmax math) ----
    float4 vreg[8];
    const float* Vt = Vbase + (size_t)kt * 32 * NKV * DH;
#pragma unroll
    for (int it = 0; it < 8; ++it) {
      const int vi = it * 256 + t;
      const int row = vi >> 6, c4 = vi & 63;
      vreg[it] = *(const float4*)(Vt + (size_t)row * NKV * DH + c4 * 4);
    }

    // ---- online softmax bookkeeping (PV layout: row pr) ----
    float mrow = -3.0e38f;
#pragma unroll 8
    for (int jj = 0; jj < 32; ++jj) mrow = fmaxf(mrow, Ps[pr][jj]);
    const float mnew = fmaxf(m, mrow);
    const float alpha = __expf(m - mnew);
    m = mnew;
    l *= alpha;
#pragma unroll
    for (int dd = 0; dd < 8; ++dd) {
      o[dd].x *= alpha; o[dd].y *= alpha; o[dd].z *= alpha; o[dd].w *= alpha;
    }

    // ---- V regs -> LDS ----
#pragma unroll
    for (int it = 0; it < 8; ++it) {
      const int vi = it * 256 + t;
      const int row = vi >> 6, c4 = vi & 63;
      *(float4*)&KVs[row][c4 * 4] = vreg[it];
    }
    __syncthreads();

    // ---- PV accumulate ----
#pragma unroll 4
    for (int jj = 0; jj < 32; ++jj) {
      const float p = __expf(Ps[pr][jj] - mnew);
      l += p;
#pragma unroll
      for (int dd = 0; dd < 8; ++dd) {
        const float4 vv = *(const float4*)&KVs[jj][pd + 32 * dd];
        o[dd].x = fmaf(p, vv.x, o[dd].x);
        o[dd].y = fmaf(p, vv.y, o[dd].y);
        o[dd].z = fmaf(p, vv.z, o[dd].z);
        o[dd].w = fmaf(p, vv.w, o[dd].w);
      }
    }
    __syncthreads();   // before next tile overwrites KVs / Ps
  }

  // ---- epilogue: normalize and store to [B,S,H*D] ----
  const float linv = 1.0f / l;
  float* Ob = O + (size_t)(b * SEQ + q0 + pr) * (NH * DH) + h * DH + pd;
#pragma unroll
  for (int dd = 0; dd < 8; ++dd) {
    float4 r = o[dd];
    r.x *= linv; r.y *= linv; r.z *= linv; r.w *= linv;
    *(float4*)(Ob + 32 * dd) = r;
  }
}

// =====================================================================
// Launch. d_in order: hidden, attention_mask(unused), wq, wk, wv, wo,
// q_scale, k_scale. Workspace: Q(33.5MB) K(8.4) V(8.4) attn(33.5) = 84MB.
// =====================================================================
extern "C" void kernel_launch(void* const* d_in, const int* in_sizes, int n_in,
                              void* d_out, int out_size, void* d_ws, size_t ws_size,
                              hipStream_t stream) {
  const float* hidden  = (const float*)d_in[0];
  const float* wq      = (const float*)d_in[2];
  const float* wk      = (const float*)d_in[3];
  const float* wv      = (const float*)d_in[4];
  const float* wo      = (const float*)d_in[5];
  const float* q_scale = (const float*)d_in[6];
  const float* k_scale = (const float*)d_in[7];
  float* out = (float*)d_out;

  float* Qb = (float*)d_ws;                       // [4096][2048]
  float* Kb = Qb + (size_t)MR * (NH * DH);        // [4096][512]
  float* Vb = Kb + (size_t)MR * (NKV * DH);       // [4096][512]
  float* Ab = Vb + (size_t)MR * (NKV * DH);       // [4096][2048]

  const dim3 blk(256);
  // Q projection: [4096,2048] @ [2048,2048]
  gemm_f32<<<dim3(HID / 128, MR / 128), blk, 0, stream>>>(hidden, wq, Qb, HID, HID);
  // K,V projections fused: [4096,2048] @ [2048,512] x2
  gemm_kv_f32<<<dim3(8, MR / 128), blk, 0, stream>>>(hidden, wk, wv, Kb, Vb, HID);
  // RMSNorm + RoPE (in-place)
  norm_rope<<<dim3(49152), blk, 0, stream>>>(Qb, Kb, Vb, q_scale, k_scale);
  // flash attention -> Ab in [B,S,H*D]
  attn_f32<<<dim3(SEQ / 32, NH, BATCH), blk, 0, stream>>>(Qb, Kb, Vb, Ab);
  // output projection: [4096,2048] @ [2048,2048]
  gemm_f32<<<dim3(HID / 128, MR / 128), blk, 0, stream>>>(Ab, wo, out, HID, HID);
}

// Round 2
// 420.635 us; speedup vs baseline: 7.7595x; 7.7595x over previous
//
#include <hip/hip_runtime.h>
#include <cstdint>
#include <cstddef>

// ---- problem constants ----
#define SEQ   2048
#define BATCH 2
#define NH    8
#define NKV   2
#define DH    256
#define HID   2048
#define MR    (BATCH*SEQ)   // 4096

typedef _Float16 h8 __attribute__((ext_vector_type(8)));
typedef _Float16 h4 __attribute__((ext_vector_type(4)));
typedef float   f32x4 __attribute__((ext_vector_type(4)));

__device__ __forceinline__ f32x4 mfma16(h8 a, h8 b, f32x4 c) {
  return __builtin_amdgcn_mfma_f32_16x16x32_f16(a, b, c, 0, 0, 0);
}
// async global->LDS, 16B per lane. LDS dest is WAVE-UNIFORM base + lane*16;
// global src is per-lane (pre-swizzled there, LDS stays linear).
__device__ __forceinline__ void gload16(const void* g, void* l) {
  __builtin_amdgcn_global_load_lds((__attribute__((address_space(1))) void*)g,
                                   (__attribute__((address_space(3))) void*)l,
                                   16, 0, 0);
}

// =====================================================================
// fp32 -> fp16 elementwise (hidden states), 4 elems/thread
// =====================================================================
__global__ __launch_bounds__(256) void cvt_f16(const float* __restrict__ in,
                                               _Float16* __restrict__ out, int n4) {
  const int i = blockIdx.x * 256 + threadIdx.x;
  if (i >= n4) return;
  const float4 v = ((const float4*)in)[i];
  h4 o = { (_Float16)v.x, (_Float16)v.y, (_Float16)v.z, (_Float16)v.w };
  ((h4*)out)[i] = o;
}

// =====================================================================
// Weight transpose + cvt: in [K][N] f32 -> out [N][K] f16. 32x32 tiles.
// =====================================================================
__global__ __launch_bounds__(256) void wtrans(const float* __restrict__ in,
                                              _Float16* __restrict__ out,
                                              int N, int K) {
  __shared__ float L[32][33];
  const int n0 = blockIdx.x * 32, k0 = blockIdx.y * 32;
  const int t = threadIdx.x;
  const int r = t >> 3, c4 = (t & 7) * 4;
  const float4 v = *(const float4*)&in[(size_t)(k0 + r) * N + n0 + c4];
  L[r][c4] = v.x; L[r][c4 + 1] = v.y; L[r][c4 + 2] = v.z; L[r][c4 + 3] = v.w;
  __syncthreads();
  h4 o = { (_Float16)L[c4][r], (_Float16)L[c4 + 1][r],
           (_Float16)L[c4 + 2][r], (_Float16)L[c4 + 3][r] };
  *(h4*)&out[(size_t)(n0 + r) * K + k0 + c4] = o;
}

// =====================================================================
// f16 MFMA GEMM: C[M,N] f32 = A[M,K] f16 @ Bt[N,K] f16 (B pre-transposed).
// 128x128 tile, 4 waves (each 64x64), BK=64, 16x16x32 MFMA.
// LDS rows 128B, XOR-swizzle byte^=((row&7)<<4) applied at the GLOBAL
// source during global_load_lds staging and re-applied on ds_read.
// =====================================================================
__global__ __launch_bounds__(256) void gemm_f16(const _Float16* __restrict__ A,
                                                const _Float16* __restrict__ Bt,
                                                float* __restrict__ C,
                                                const int N, const int K) {
  __shared__ __align__(16) unsigned char sm[32768];   // A [0,16K), B [16K,32K)
  const int t = threadIdx.x, w = t >> 6, lane = t & 63;
  const int l15 = lane & 15, l4 = lane >> 4;
  const int wr = w >> 1, wc = w & 1;
  const int m0 = blockIdx.y * 128, n0 = blockIdx.x * 128;
  const int swz = (l15 & 7) << 4;
  const size_t rb = (size_t)K * 2;           // row bytes

  int rS[4], cS[4];                          // staging geometry (A and B identical)
#pragma unroll
  for (int i = 0; i < 4; ++i) {
    const int o = i * 4096 + w * 1024 + lane * 16;
    rS[i] = o >> 7;
    cS[i] = (o & 127) ^ ((rS[i] & 7) << 4);
  }
  const char* Ab = (const char*)A + (size_t)m0 * rb;
  const char* Bb = (const char*)Bt + (size_t)n0 * rb;

  f32x4 acc[4][4] = {};

  for (int k0 = 0; k0 < K; k0 += 64) {
    __syncthreads();
#pragma unroll
    for (int i = 0; i < 4; ++i) {
      gload16(Ab + (size_t)rS[i] * rb + k0 * 2 + cS[i], sm + i * 4096 + w * 1024);
      gload16(Bb + (size_t)rS[i] * rb + k0 * 2 + cS[i], sm + 16384 + i * 4096 + w * 1024);
    }
    __syncthreads();
#pragma unroll
    for (int kk = 0; kk < 2; ++kk) {
      const int ko = (kk * 64 + l4 * 16) ^ swz;
      h8 av[4], bv[4];
#pragma unroll
      for (int f = 0; f < 4; ++f) {
        av[f] = *(const h8*)(sm + (wr * 64 + f * 16 + l15) * 128 + ko);
        bv[f] = *(const h8*)(sm + 16384 + (wc * 64 + f * 16 + l15) * 128 + ko);
      }
#pragma unroll
      for (int i = 0; i < 4; ++i)
#pragma unroll
        for (int j = 0; j < 4; ++j)
          acc[i][j] = mfma16(av[i], bv[j], acc[i][j]);
    }
  }
  // C/D layout (m89): col = lane&15, row = (lane>>4)*4 + reg
#pragma unroll
  for (int i = 0; i < 4; ++i)
#pragma unroll
    for (int r = 0; r < 4; ++r) {
      const int row = m0 + wr * 64 + i * 16 + l4 * 4 + r;
      float* Cp = C + (size_t)row * N + n0 + wc * 64 + l15;
#pragma unroll
      for (int j = 0; j < 4; ++j) Cp[j * 16] = acc[i][j][r];
    }
}

// =====================================================================
// RMSNorm(+q_scale)+RoPE for Q: in Qp f32 [b*s][h*256], out Qh f16 [b][h][s][256]
// =====================================================================
__global__ __launch_bounds__(256) void norm_rope_q(const float* __restrict__ Qp,
                                                   _Float16* __restrict__ Qh,
                                                   const float* __restrict__ q_scale) {
  const int idx = blockIdx.x;           // ((b*2048+s)*8 + h)
  const int t = threadIdx.x;
  const int h = idx & 7;
  const int bs = idx >> 3;
  const int s = bs & (SEQ - 1);
  const int b = bs >> 11;
  const float x = Qp[(size_t)bs * 2048 + h * 256 + t];
  float ss = x * x;
#pragma unroll
  for (int off = 32; off; off >>= 1) ss += __shfl_xor(ss, off);
  __shared__ float red[4];
  if ((t & 63) == 0) red[t >> 6] = ss;
  __syncthreads();
  const float tot = red[0] + red[1] + red[2] + red[3];
  const float inv = rsqrtf(tot * (1.0f / 256.0f) + 1e-6f);
  const float xn = x * inv * q_scale[t];
  __shared__ float rowbuf[256];
  rowbuf[t] = xn;
  __syncthreads();
  const int f = t & 127;
  const float invf = expf(-0.07195578415606391f * (float)f);   // 10000^(-f/128)
  float sn, cs;
  sincosf((float)s * invf, &sn, &cs);
  const float other = rowbuf[t ^ 128];
  const float o = (t < 128) ? (xn * cs - other * sn) : (xn * cs + other * sn);
  Qh[((size_t)(b * NH + h) * SEQ + s) * DH + t] = (_Float16)o;
}

// =====================================================================
// RMSNorm(+rope,k_scale) for K rows and RMSNorm-only for V rows.
// in KVp f32 [b*s][1024] (cols 0-511 = K, 512-1023 = V)
// out Kh/Vh f16 [b][kv][s][256]
// =====================================================================
__global__ __launch_bounds__(256) void norm_kv(const float* __restrict__ KVp,
                                               _Float16* __restrict__ Kh,
                                               _Float16* __restrict__ Vh,
                                               const float* __restrict__ k_scale) {
  const int idx = blockIdx.x;
  const int t = threadIdx.x;
  const bool isK = idx < 8192;
  const int i = isK ? idx : idx - 8192;   // ((b*2048+s)*2 + kv)
  const int kv = i & 1;
  const int bs = i >> 1;
  const int s = bs & (SEQ - 1);
  const int b = bs >> 11;
  const int col = (isK ? kv * DH : 512 + kv * DH) + t;
  const float x = KVp[(size_t)bs * 1024 + col];
  float ss = x * x;
#pragma unroll
  for (int off = 32; off; off >>= 1) ss += __shfl_xor(ss, off);
  __shared__ float red[4];
  if ((t & 63) == 0) red[t >> 6] = ss;
  __syncthreads();
  const float tot = red[0] + red[1] + red[2] + red[3];
  const float inv = rsqrtf(tot * (1.0f / 256.0f) + 1e-6f);
  float xn = x * inv;
  const size_t o = ((size_t)(b * NKV + kv) * SEQ + s) * DH + t;
  if (isK) {                                    // uniform per block
    xn *= k_scale[t];
    __shared__ float rowbuf[256];
    rowbuf[t] = xn;
    __syncthreads();
    const int f = t & 127;
    const float invf = expf(-0.07195578415606391f * (float)f);
    float sn, cs;
    sincosf((float)s * invf, &sn, &cs);
    const float other = rowbuf[t ^ 128];
    const float ov = (t < 128) ? (xn * cs - other * sn) : (xn * cs + other * sn);
    Kh[o] = (_Float16)ov;
  } else {
    Vh[o] = (_Float16)xn;
  }
}

// =====================================================================
// V transpose: per (b,kv): [2048 s][256 d] -> Vt [256 d][2048 s]. 32x32 tiles.
// =====================================================================
__global__ __launch_bounds__(256) void transpose_v(const _Float16* __restrict__ Vh,
                                                   _Float16* __restrict__ Vt) {
  __shared__ _Float16 L[32][36];
  const int s0 = blockIdx.x * 32, d0 = blockIdx.y * 32;
  const size_t base = (size_t)blockIdx.z * SEQ * DH;
  const int t = threadIdx.x;
  const int r = t >> 3, c4 = (t & 7) * 4;
  const h4 v = *(const h4*)&Vh[base + (size_t)(s0 + r) * DH + d0 + c4];
  L[r][c4] = v.x; L[r][c4 + 1] = v.y; L[r][c4 + 2] = v.z; L[r][c4 + 3] = v.w;
  __syncthreads();
  h4 o = { L[c4][r], L[c4 + 1][r], L[c4 + 2][r], L[c4 + 3][r] };
  *(h4*)&Vt[base + (size_t)(d0 + r) * SEQ + s0 + c4] = o;
}

// =====================================================================
// Flash attention, f16 MFMA, causal, GQA (head h -> kv head h>>2).
// Block: 256 thr (4 waves), processes TWO q-tiles of 64 rows (qt, 31-qt)
// -> uniform 33 k-tiles of work per block; grid 16x8x2 = 256 blocks.
// Wave w owns q-rows [w*16, w*16+16). Q in registers. K,Vt staged in LDS
// (XOR-swizzled via pre-swizzled global source). P goes through per-wave
// swizzled LDS (overlaid on K region after a barrier).
// =====================================================================
__global__ __launch_bounds__(256) void attn_f16(const _Float16* __restrict__ Qh,
                                                const _Float16* __restrict__ Kh,
                                                const _Float16* __restrict__ Vt,
                                                _Float16* __restrict__ Ah) {
  __shared__ __align__(16) unsigned char sm[65536];  // K [0,32K), Vt [32K,64K); P at w*2048
  const int pid = blockIdx.x;          // 0..15
  const int h = blockIdx.y, b = blockIdx.z;
  const int kh = h >> 2;
  const int t = threadIdx.x, w = t >> 6, lane = t & 63;
  const int l15 = lane & 15, l4 = lane >> 4;
  const int swz = (l15 & 7) << 4;

  const char* Qg = (const char*)(Qh + (size_t)(b * NH + h) * SEQ * DH);
  const char* Kg = (const char*)(Kh + (size_t)(b * NKV + kh) * SEQ * DH);
  const char* Vg = (const char*)(Vt + (size_t)(b * NKV + kh) * DH * SEQ);

  for (int half = 0; half < 2; ++half) {
    const int qt = (half == 0) ? pid : 31 - pid;
    const int q0 = qt * 64;

    // ---- stage Q tile into K region, load fragments to registers ----
    __syncthreads();
#pragma unroll
    for (int i = 0; i < 8; ++i) {
      const int o = i * 4096 + w * 1024 + lane * 16;
      const int row = o >> 9;
      const int off = (o & 511) ^ ((row & 7) << 4);
      gload16(Qg + (size_t)(q0 + row) * 512 + off, sm + i * 4096 + w * 1024);
    }
    __syncthreads();
    h8 qf[8];
    {
      const int qrow = w * 16 + l15;
#pragma unroll
      for (int dc = 0; dc < 8; ++dc)
        qf[dc] = *(const h8*)(sm + qrow * 512 + ((dc * 64 + l4 * 16) ^ swz));
    }
    f32x4 o_acc[16] = {};
    float mrun[4] = { -3e38f, -3e38f, -3e38f, -3e38f };
    float lrun[4] = { 0.f, 0.f, 0.f, 0.f };

    for (int kt = 0; kt <= qt; ++kt) {
      __syncthreads();    // previous tile's LDS reads (and Q frag reads) done
#pragma unroll
      for (int i = 0; i < 8; ++i) {
        const int o = i * 4096 + w * 1024 + lane * 16;
        const int row = o >> 9;
        const int off = (o & 511) ^ ((row & 7) << 4);
        gload16(Kg + (size_t)(kt * 64 + row) * 512 + off, sm + i * 4096 + w * 1024);
        const int d = o >> 7;
        const int voff = (o & 127) ^ ((d & 7) << 4);
        gload16(Vg + (size_t)d * (SEQ * 2) + kt * 128 + voff,
                sm + 32768 + i * 4096 + w * 1024);
      }
      __syncthreads();

      // ---- QK^T: scores for 16 q x 64 k ----
      f32x4 sc[4];
#pragma unroll
      for (int fk = 0; fk < 4; ++fk) {
        f32x4 z = {};
        sc[fk] = z;
        const int krow = fk * 16 + l15;
#pragma unroll
        for (int dc = 0; dc < 8; ++dc) {
          h8 kf = *(const h8*)(sm + krow * 512 + ((dc * 64 + l4 * 16) ^ swz));
          sc[fk] = mfma16(qf[dc], kf, sc[fk]);
        }
      }

      // ---- mask + scale + online softmax (row r: q = q0+w*16+l4*4+r) ----
      float p[4][4], alpha[4], mnew[4];
#pragma unroll
      for (int r = 0; r < 4; ++r) {
        const int qg = q0 + w * 16 + l4 * 4 + r;
        float mx = -3e38f;
#pragma unroll
        for (int fk = 0; fk < 4; ++fk) {
          const int kg = kt * 64 + fk * 16 + l15;
          float sv = sc[fk][r] * 0.0625f;           // 1/sqrt(256)
          sv = (kg <= qg) ? sv : -3e38f;
          p[fk][r] = sv;
          mx = fmaxf(mx, sv);
        }
#pragma unroll
        for (int msk = 1; msk < 16; msk <<= 1) mx = fmaxf(mx, __shfl_xor(mx, msk));
        mnew[r] = fmaxf(mrun[r], mx);
        alpha[r] = __expf(mrun[r] - mnew[r]);
        mrun[r] = mnew[r];
        float ls = 0.f;
#pragma unroll
        for (int fk = 0; fk < 4; ++fk) {
          const float e = __expf(p[fk][r] - mnew[r]);
          p[fk][r] = e;
          ls += e;
        }
#pragma unroll
        for (int msk = 1; msk < 16; msk <<= 1) ls += __shfl_xor(ls, msk);
        lrun[r] = lrun[r] * alpha[r] + ls;
      }
#pragma unroll
      for (int fd = 0; fd < 16; ++fd)
#pragma unroll
        for (int r = 0; r < 4; ++r) o_acc[fd][r] *= alpha[r];

      __syncthreads();   // all waves done reading K region -> safe to overlay P

      // ---- P -> per-wave swizzled LDS (bf-rows 128B), then PV ----
      unsigned char* Pb = sm + w * 2048;
#pragma unroll
      for (int fk = 0; fk < 4; ++fk)
#pragma unroll
        for (int r = 0; r < 4; ++r) {
          const int qrow = l4 * 4 + r, k = fk * 16 + l15;
          *(_Float16*)(Pb + qrow * 128 + ((k * 2) ^ ((qrow & 7) << 4))) =
              (_Float16)p[fk][r];
        }
#pragma unroll
      for (int kk = 0; kk < 2; ++kk) {
        const h8 pa = *(const h8*)(Pb + l15 * 128 + ((kk * 64 + l4 * 16) ^ swz));
#pragma unroll
        for (int fd = 0; fd < 16; ++fd) {
          const int d = fd * 16 + l15;
          h8 vf = *(const h8*)(sm + 32768 + d * 128 + ((kk * 64 + l4 * 16) ^ swz));
          o_acc[fd] = mfma16(pa, vf, o_acc[fd]);
        }
      }
    }

    // ---- epilogue: /l, store f16 to [b][s][h*256] ----
#pragma unroll
    for (int r = 0; r < 4; ++r) {
      const float linv = 1.0f / lrun[r];
      const int srow = q0 + w * 16 + l4 * 4 + r;
      _Float16* Op = Ah + (size_t)(b * SEQ + srow) * (NH * DH) + h * DH + l15;
#pragma unroll
      for (int fd = 0; fd < 16; ++fd)
        Op[fd * 16] = (_Float16)(o_acc[fd][r] * linv);
    }
  }
}

// =====================================================================
// Launch. d_in: hidden, mask(unused), wq, wk, wv, wo, q_scale, k_scale.
// =====================================================================
extern "C" void kernel_launch(void* const* d_in, const int* in_sizes, int n_in,
                              void* d_out, int out_size, void* d_ws, size_t ws_size,
                              hipStream_t stream) {
  (void)in_sizes; (void)n_in; (void)out_size; (void)ws_size;
  const float* hidden  = (const float*)d_in[0];
  const float* wq      = (const float*)d_in[2];
  const float* wk      = (const float*)d_in[3];
  const float* wv      = (const float*)d_in[4];
  const float* wo      = (const float*)d_in[5];
  const float* q_scale = (const float*)d_in[6];
  const float* k_scale = (const float*)d_in[7];
  float* out = (float*)d_out;

  uint8_t* ws = (uint8_t*)d_ws;
  _Float16* hid_h = (_Float16*)ws;            ws += (size_t)MR * HID * 2;        // 16.78MB
  _Float16* wq_t  = (_Float16*)ws;            ws += (size_t)HID * HID * 2;       // 8.39MB (reused for wo_t)
  _Float16* wkv_t = (_Float16*)ws;            ws += (size_t)1024 * HID * 2;      // 4.19MB
  float*    Qp    = (float*)ws;               ws += (size_t)MR * HID * 4;        // 33.55MB (reused as Ah)
  float*    KVp   = (float*)ws;               ws += (size_t)MR * 1024 * 4;       // 16.78MB
  _Float16* Qh    = (_Float16*)ws;            ws += (size_t)MR * HID * 2;        // 16.78MB
  _Float16* Kh    = (_Float16*)ws;            ws += (size_t)MR * 512 * 2;        // 4.19MB
  _Float16* Vh    = (_Float16*)ws;            ws += (size_t)MR * 512 * 2;        // 4.19MB
  _Float16* Vt    = (_Float16*)ws;            ws += (size_t)MR * 512 * 2;        // 4.19MB
  _Float16* Ah    = (_Float16*)Qp;            // overlay (Qp dead after norm_rope_q)

  const dim3 blk(256);
  cvt_f16<<<dim3(8192), blk, 0, stream>>>(hidden, hid_h, MR * HID / 4);
  wtrans<<<dim3(64, 64), blk, 0, stream>>>(wq, wq_t, 2048, 2048);
  wtrans<<<dim3(16, 64), blk, 0, stream>>>(wk, wkv_t, 512, 2048);
  wtrans<<<dim3(16, 64), blk, 0, stream>>>(wv, wkv_t + (size_t)512 * 2048, 512, 2048);
  gemm_f16<<<dim3(16, 32), blk, 0, stream>>>(hid_h, wq_t, Qp, 2048, 2048);
  gemm_f16<<<dim3(8, 32), blk, 0, stream>>>(hid_h, wkv_t, KVp, 1024, 2048);
  wtrans<<<dim3(64, 64), blk, 0, stream>>>(wo, wq_t, 2048, 2048);   // wo_t into wq_t (dead)
  norm_rope_q<<<dim3(32768), blk, 0, stream>>>(Qp, Qh, q_scale);
  norm_kv<<<dim3(16384), blk, 0, stream>>>(KVp, Kh, Vh, k_scale);
  transpose_v<<<dim3(64, 8, 4), blk, 0, stream>>>(Vh, Vt);
  attn_f16<<<dim3(16, 8, 2), blk, 0, stream>>>(Qh, Kh, Vt, Ah);
  gemm_f16<<<dim3(16, 32), blk, 0, stream>>>(Ah, wq_t, out, 2048, 2048);
}

// Round 5
// 395.028 us; speedup vs baseline: 8.2625x; 1.0648x over previous
//
#include <hip/hip_runtime.h>
#include <cstdint>
#include <cstddef>

// ---- problem constants ----
#define SEQ   2048
#define BATCH 2
#define NH    8
#define NKV   2
#define DH    256
#define HID   2048
#define MR    (BATCH*SEQ)   // 4096

typedef _Float16 h8 __attribute__((ext_vector_type(8)));
typedef _Float16 h4 __attribute__((ext_vector_type(4)));
typedef float   f32x4 __attribute__((ext_vector_type(4)));
typedef int     i32x4 __attribute__((ext_vector_type(4)));

__device__ __forceinline__ f32x4 mfma16(h8 a, h8 b, f32x4 c) {
  return __builtin_amdgcn_mfma_f32_16x16x32_f16(a, b, c, 0, 0, 0);
}
// async global->LDS, 16B/lane. LDS dest = wave-uniform base + lane*16 (linear);
// swizzle is applied on the GLOBAL source address instead.
__device__ __forceinline__ void gload16(const void* g, void* l) {
  __builtin_amdgcn_global_load_lds((__attribute__((address_space(1))) void*)g,
                                   (__attribute__((address_space(3))) void*)l,
                                   16, 0, 0);
}
__device__ __forceinline__ int pkf16(float a, float b) {   // {lo=a, hi=b} f16
  auto t = __builtin_amdgcn_cvt_pkrtz(a, b);   // __fp16 ext_vector(2)
  return __builtin_bit_cast(int, t);
}

// =====================================================================
// fp32 -> fp16 elementwise (hidden states), 4 elems/thread
// =====================================================================
__global__ __launch_bounds__(256) void cvt_f16(const float* __restrict__ in,
                                               _Float16* __restrict__ out, int n4) {
  const int i = blockIdx.x * 256 + threadIdx.x;
  if (i >= n4) return;
  const float4 v = ((const float4*)in)[i];
  h4 o = { (_Float16)v.x, (_Float16)v.y, (_Float16)v.z, (_Float16)v.w };
  ((h4*)out)[i] = o;
}

// =====================================================================
// Weight transpose + cvt: in [K][N] f32 -> out [N][K] f16. 32x32 tiles.
// =====================================================================
__global__ __launch_bounds__(256) void wtrans(const float* __restrict__ in,
                                              _Float16* __restrict__ out,
                                              int N, int K) {
  __shared__ float L[32][33];
  const int n0 = blockIdx.x * 32, k0 = blockIdx.y * 32;
  const int t = threadIdx.x;
  const int r = t >> 3, c4 = (t & 7) * 4;
  const float4 v = *(const float4*)&in[(size_t)(k0 + r) * N + n0 + c4];
  L[r][c4] = v.x; L[r][c4 + 1] = v.y; L[r][c4 + 2] = v.z; L[r][c4 + 3] = v.w;
  __syncthreads();
  h4 o = { (_Float16)L[c4][r], (_Float16)L[c4 + 1][r],
           (_Float16)L[c4 + 2][r], (_Float16)L[c4 + 3][r] };
  *(h4*)&out[(size_t)(n0 + r) * K + k0 + c4] = o;
}

// =====================================================================
// f16 MFMA GEMM: C[M,N] f32 = A[M,K] f16 @ Bt[N,K] f16 (B pre-transposed).
// 128x128 tile, 4 waves (each 64x64), BK=64, 16x16x32 MFMA.
// LDS rows 128B, XOR-swizzle byte^=((row&7)<<4): pre-swizzled global src
// during global_load_lds staging, re-applied on ds_read.
// =====================================================================
__global__ __launch_bounds__(256) void gemm_f16(const _Float16* __restrict__ A,
                                                const _Float16* __restrict__ Bt,
                                                float* __restrict__ C,
                                                const int N, const int K) {
  __shared__ __align__(16) unsigned char sm[32768];   // A [0,16K), B [16K,32K)
  const int t = threadIdx.x, w = t >> 6, lane = t & 63;
  const int l15 = lane & 15, l4 = lane >> 4;
  const int wr = w >> 1, wc = w & 1;
  const int m0 = blockIdx.y * 128, n0 = blockIdx.x * 128;
  const int swz = (l15 & 7) << 4;
  const size_t rb = (size_t)K * 2;           // row bytes

  int rS[4], cS[4];                          // staging geometry (A and B identical)
#pragma unroll
  for (int i = 0; i < 4; ++i) {
    const int o = i * 4096 + w * 1024 + lane * 16;
    rS[i] = o >> 7;
    cS[i] = (o & 127) ^ ((rS[i] & 7) << 4);
  }
  const char* Ab = (const char*)A + (size_t)m0 * rb;
  const char* Bb = (const char*)Bt + (size_t)n0 * rb;

  f32x4 acc[4][4] = {};

  for (int k0 = 0; k0 < K; k0 += 64) {
    __syncthreads();
#pragma unroll
    for (int i = 0; i < 4; ++i) {
      gload16(Ab + (size_t)rS[i] * rb + k0 * 2 + cS[i], sm + i * 4096 + w * 1024);
      gload16(Bb + (size_t)rS[i] * rb + k0 * 2 + cS[i], sm + 16384 + i * 4096 + w * 1024);
    }
    __syncthreads();
#pragma unroll
    for (int kk = 0; kk < 2; ++kk) {
      const int ko = (kk * 64 + l4 * 16) ^ swz;
      h8 av[4], bv[4];
#pragma unroll
      for (int f = 0; f < 4; ++f) {
        av[f] = *(const h8*)(sm + (wr * 64 + f * 16 + l15) * 128 + ko);
        bv[f] = *(const h8*)(sm + 16384 + (wc * 64 + f * 16 + l15) * 128 + ko);
      }
#pragma unroll
      for (int i = 0; i < 4; ++i)
#pragma unroll
        for (int j = 0; j < 4; ++j)
          acc[i][j] = mfma16(av[i], bv[j], acc[i][j]);
    }
  }
  // C/D layout: col = lane&15, row = (lane>>4)*4 + reg
#pragma unroll
  for (int i = 0; i < 4; ++i)
#pragma unroll
    for (int r = 0; r < 4; ++r) {
      const int row = m0 + wr * 64 + i * 16 + l4 * 4 + r;
      float* Cp = C + (size_t)row * N + n0 + wc * 64 + l15;
#pragma unroll
      for (int j = 0; j < 4; ++j) Cp[j * 16] = acc[i][j][r];
    }
}

// =====================================================================
// RMSNorm(+q_scale)+RoPE for Q rows of fused QKVp [4096][3072].
// Also folds the softmax 1/sqrt(256) into Q. Out: Qh f16 [b][h][s][256].
// =====================================================================
__global__ __launch_bounds__(256) void norm_rope_q(const float* __restrict__ QKVp,
                                                   _Float16* __restrict__ Qh,
                                                   const float* __restrict__ q_scale) {
  const int idx = blockIdx.x;           // ((b*2048+s)*8 + h)
  const int t = threadIdx.x;
  const int h = idx & 7;
  const int bs = idx >> 3;
  const int s = bs & (SEQ - 1);
  const int b = bs >> 11;
  const float x = QKVp[(size_t)bs * 3072 + h * 256 + t];
  float ss = x * x;
#pragma unroll
  for (int off = 32; off; off >>= 1) ss += __shfl_xor(ss, off);
  __shared__ float red[4];
  if ((t & 63) == 0) red[t >> 6] = ss;
  __syncthreads();
  const float tot = red[0] + red[1] + red[2] + red[3];
  const float inv = rsqrtf(tot * (1.0f / 256.0f) + 1e-6f);
  const float xn = x * inv * q_scale[t];
  __shared__ float rowbuf[256];
  rowbuf[t] = xn;
  __syncthreads();
  const int f = t & 127;
  const float invf = expf(-0.07195578415606391f * (float)f);   // 10000^(-f/128)
  float sn, cs;
  sincosf((float)s * invf, &sn, &cs);
  const float other = rowbuf[t ^ 128];
  const float o = (t < 128) ? (xn * cs - other * sn) : (xn * cs + other * sn);
  Qh[((size_t)(b * NH + h) * SEQ + s) * DH + t] = (_Float16)(o * 0.0625f);
}

// =====================================================================
// RMSNorm(+rope,k_scale) for K rows, RMSNorm-only for V rows of QKVp.
// K cols 2048+kv*256, V cols 2560+kv*256. Out: Kh/Vh f16 [b][kv][s][256].
// =====================================================================
__global__ __launch_bounds__(256) void norm_kv(const float* __restrict__ QKVp,
                                               _Float16* __restrict__ Kh,
                                               _Float16* __restrict__ Vh,
                                               const float* __restrict__ k_scale) {
  const int idx = blockIdx.x;
  const int t = threadIdx.x;
  const bool isK = idx < 8192;
  const int i = isK ? idx : idx - 8192;   // ((b*2048+s)*2 + kv)
  const int kv = i & 1;
  const int bs = i >> 1;
  const int s = bs & (SEQ - 1);
  const int b = bs >> 11;
  const int col = (isK ? 2048 + kv * DH : 2560 + kv * DH) + t;
  const float x = QKVp[(size_t)bs * 3072 + col];
  float ss = x * x;
#pragma unroll
  for (int off = 32; off; off >>= 1) ss += __shfl_xor(ss, off);
  __shared__ float red[4];
  if ((t & 63) == 0) red[t >> 6] = ss;
  __syncthreads();
  const float tot = red[0] + red[1] + red[2] + red[3];
  const float inv = rsqrtf(tot * (1.0f / 256.0f) + 1e-6f);
  float xn = x * inv;
  const size_t o = ((size_t)(b * NKV + kv) * SEQ + s) * DH + t;
  if (isK) {
    xn *= k_scale[t];
    __shared__ float rowbuf[256];
    rowbuf[t] = xn;
    __syncthreads();
    const int f = t & 127;
    const float invf = expf(-0.07195578415606391f * (float)f);
    float sn, cs;
    sincosf((float)s * invf, &sn, &cs);
    const float other = rowbuf[t ^ 128];
    const float ov = (t < 128) ? (xn * cs - other * sn) : (xn * cs + other * sn);
    Kh[o] = (_Float16)ov;
  } else {
    Vh[o] = (_Float16)xn;
  }
}

// =====================================================================
// V transpose: per (b,kv): [2048 s][256 d] -> Vt [256 d][2048 s]. 32x32 tiles.
// =====================================================================
__global__ __launch_bounds__(256) void transpose_v(const _Float16* __restrict__ Vh,
                                                   _Float16* __restrict__ Vt) {
  __shared__ _Float16 L[32][36];
  const int s0 = blockIdx.x * 32, d0 = blockIdx.y * 32;
  const size_t base = (size_t)blockIdx.z * SEQ * DH;
  const int t = threadIdx.x;
  const int r = t >> 3, c4 = (t & 7) * 4;
  const h4 v = *(const h4*)&Vh[base + (size_t)(s0 + r) * DH + d0 + c4];
  L[r][c4] = v.x; L[r][c4 + 1] = v.y; L[r][c4 + 2] = v.z; L[r][c4 + 3] = v.w;
  __syncthreads();
  h4 o = { L[c4][r], L[c4 + 1][r], L[c4 + 2][r], L[c4 + 3][r] };
  *(h4*)&Vt[base + (size_t)(d0 + r) * SEQ + s0 + c4] = o;
}

// =====================================================================
// Flash attention, f16 MFMA, causal, GQA (head h -> kv head h>>2).
// ONE 64-row q-tile per block, 4 waves (wave w: q-rows w*16..w*16+15).
// grid (32,8,2) = 512 blocks = 2 blocks/CU (launch_bounds(256,2), 64KB LDS).
// Work balance: qt = b ? 31-pid : pid -> co-resident partner blocks
// have complementary causal depth.
// SWAPPED QK^T: sc = mfma(K,Q) puts P at (q=l15, k=l4*4+reg); softmax
// reduces with 2 shfl_xor; P->f16 A-fragments rebuilt fully in-register.
// NOTE: all __shfl calls are in UNIFORM control flow (convergent ops in a
// divergent ternary produced undefined reads in R4 -> hoisted + select).
// =====================================================================
__global__ __launch_bounds__(256, 2) void attn_f16(const _Float16* __restrict__ Qh,
                                                   const _Float16* __restrict__ Kh,
                                                   const _Float16* __restrict__ Vt,
                                                   _Float16* __restrict__ Ah) {
  __shared__ __align__(16) unsigned char sm[65536];  // K [0,32K), Vt [32K,64K)
  const int pid = blockIdx.x;          // 0..31
  const int h = blockIdx.y, b = blockIdx.z;
  const int kh = h >> 2;
  const int qt = b ? (31 - pid) : pid;
  const int q0 = qt * 64;
  const int t = threadIdx.x, w = t >> 6, lane = t & 63;
  const int l15 = lane & 15, l4 = lane >> 4;
  const int swz = (l15 & 7) << 4;

  const char* Qg = (const char*)(Qh + (size_t)(b * NH + h) * SEQ * DH);
  const char* Kg = (const char*)(Kh + (size_t)(b * NKV + kh) * SEQ * DH);
  const char* Vg = (const char*)(Vt + (size_t)(b * NKV + kh) * DH * SEQ);

  // ---- stage Q tile into K region, load fragments to registers ----
#pragma unroll
  for (int i = 0; i < 8; ++i) {
    const int o = i * 4096 + w * 1024 + lane * 16;
    const int row = o >> 9;
    const int off = (o & 511) ^ ((row & 7) << 4);
    gload16(Qg + (size_t)(q0 + row) * 512 + off, sm + i * 4096 + w * 1024);
  }
  __syncthreads();
  h8 qf[8];
  {
    const int qrow = w * 16 + l15;
#pragma unroll
    for (int dc = 0; dc < 8; ++dc)
      qf[dc] = *(const h8*)(sm + qrow * 512 + ((dc * 64 + l4 * 16) ^ swz));
  }
  f32x4 o_acc[16] = {};
  float mrun = -3e38f, lrun = 0.f;     // stats for q = q0 + w*16 + l15

  for (int kt = 0; kt <= qt; ++kt) {
    __syncthreads();    // prev tile's LDS reads (or Q frag reads) done
#pragma unroll
    for (int i = 0; i < 8; ++i) {
      const int o = i * 4096 + w * 1024 + lane * 16;
      const int row = o >> 9;
      const int off = (o & 511) ^ ((row & 7) << 4);
      gload16(Kg + (size_t)(kt * 64 + row) * 512 + off, sm + i * 4096 + w * 1024);
      const int d = o >> 7;
      const int voff = (o & 127) ^ ((d & 7) << 4);
      gload16(Vg + (size_t)d * (SEQ * 2) + kt * 128 + voff,
              sm + 32768 + i * 4096 + w * 1024);
    }
    __syncthreads();

    // ---- QK^T (swapped): sc[fk] = K-rows x Q-rows ----
    f32x4 sc[4];
    __builtin_amdgcn_s_setprio(1);
#pragma unroll
    for (int fk = 0; fk < 4; ++fk) {
      f32x4 z = {};
      sc[fk] = z;
      const int krow = fk * 16 + l15;
#pragma unroll
      for (int dc = 0; dc < 8; ++dc) {
        const h8 kf = *(const h8*)(sm + krow * 512 + ((dc * 64 + l4 * 16) ^ swz));
        sc[fk] = mfma16(kf, qf[dc], sc[fk]);
      }
    }
    __builtin_amdgcn_s_setprio(0);

    // ---- mask (diagonal tile only) + online softmax, all in-register ----
    // lane holds P[q = q0+w*16+l15][k = kt*64 + fk*16 + l4*4 + r]
    float e[4][4];
    if (kt == qt) {
#pragma unroll
      for (int fk = 0; fk < 4; ++fk)
#pragma unroll
        for (int r = 0; r < 4; ++r)
          e[fk][r] = (fk * 16 + l4 * 4 + r <= w * 16 + l15) ? sc[fk][r] : -3e38f;
    } else {
#pragma unroll
      for (int fk = 0; fk < 4; ++fk)
#pragma unroll
        for (int r = 0; r < 4; ++r) e[fk][r] = sc[fk][r];
    }
    float pm = -3e38f;
#pragma unroll
    for (int fk = 0; fk < 4; ++fk)
#pragma unroll
      for (int r = 0; r < 4; ++r) pm = fmaxf(pm, e[fk][r]);
    pm = fmaxf(pm, __shfl_xor(pm, 16));
    pm = fmaxf(pm, __shfl_xor(pm, 32));
    const float mnew = fmaxf(mrun, pm);
    const float alpha = __expf(mrun - mnew);
    mrun = mnew;
    float ls = 0.f;
#pragma unroll
    for (int fk = 0; fk < 4; ++fk)
#pragma unroll
      for (int r = 0; r < 4; ++r) {
        e[fk][r] = __expf(e[fk][r] - mnew);
        ls += e[fk][r];
      }
    ls += __shfl_xor(ls, 16);
    ls += __shfl_xor(ls, 32);
    lrun = lrun * alpha + ls;

    // rescale O (alpha lives at q=l15; O rows live at q=l4*4+r)
    float al[4];
#pragma unroll
    for (int r = 0; r < 4; ++r) al[r] = __shfl(alpha, l4 * 4 + r);
#pragma unroll
    for (int fd = 0; fd < 16; ++fd)
#pragma unroll
      for (int r = 0; r < 4; ++r) o_acc[fd][r] *= al[r];

    // ---- P -> A-fragments in-register: pack f16 pairs, shfl-redistribute ----
    // owned dwords (per kk): d0={k:l4*4+0,1} d1={+2,3} of frag 2kk;
    //                        d2,d3 same of frag 2kk+1 (k offset +16).
    // needed (dest l4): k = kk*32 + l4*8 + 0..7.
    // ALL shfls unconditional (uniform flow); select afterwards.
    h8 pa[2];
    const int src0 = l15 + ((l4 & 1) << 5);   // lane of l4' = 2*(l4&1)
    const int src1 = src0 + 16;               // lane of l4' = 2*(l4&1)+1
    const bool lowk = (l4 < 2);
#pragma unroll
    for (int kk = 0; kk < 2; ++kk) {
      const int d0 = pkf16(e[2 * kk][0], e[2 * kk][1]);
      const int d1 = pkf16(e[2 * kk][2], e[2 * kk][3]);
      const int d2 = pkf16(e[2 * kk + 1][0], e[2 * kk + 1][1]);
      const int d3 = pkf16(e[2 * kk + 1][2], e[2 * kk + 1][3]);
      const int s00 = __shfl(d0, src0);
      const int s10 = __shfl(d1, src0);
      const int s20 = __shfl(d2, src0);
      const int s30 = __shfl(d3, src0);
      const int s01 = __shfl(d0, src1);
      const int s11 = __shfl(d1, src1);
      const int s21 = __shfl(d2, src1);
      const int s31 = __shfl(d3, src1);
      const int n0 = lowk ? s00 : s20;
      const int n1 = lowk ? s10 : s30;
      const int n2 = lowk ? s01 : s21;
      const int n3 = lowk ? s11 : s31;
      i32x4 pw = { n0, n1, n2, n3 };
      pa[kk] = __builtin_bit_cast(h8, pw);
    }

    // ---- PV: O[q][d] += P[q][k] V[k][d] ----
    __builtin_amdgcn_s_setprio(1);
#pragma unroll
    for (int kk = 0; kk < 2; ++kk) {
      const int ko = (kk * 64 + l4 * 16) ^ swz;
#pragma unroll
      for (int fd = 0; fd < 16; ++fd) {
        const h8 vf = *(const h8*)(sm + 32768 + (fd * 16 + l15) * 128 + ko);
        o_acc[fd] = mfma16(pa[kk], vf, o_acc[fd]);
      }
    }
    __builtin_amdgcn_s_setprio(0);
  }

  // ---- epilogue: /l (stats at q=l15 -> rows q=l4*4+r via shfl), store ----
  const float inv = 1.0f / lrun;
#pragma unroll
  for (int r = 0; r < 4; ++r) {
    const float linv = __shfl(inv, l4 * 4 + r);
    const int srow = q0 + w * 16 + l4 * 4 + r;
    _Float16* Op = Ah + (size_t)(b * SEQ + srow) * (NH * DH) + h * DH + l15;
#pragma unroll
    for (int fd = 0; fd < 16; ++fd)
      Op[fd * 16] = (_Float16)(o_acc[fd][r] * linv);
  }
}

// =====================================================================
// Launch. d_in: hidden, mask(unused), wq, wk, wv, wo, q_scale, k_scale.
// =====================================================================
extern "C" void kernel_launch(void* const* d_in, const int* in_sizes, int n_in,
                              void* d_out, int out_size, void* d_ws, size_t ws_size,
                              hipStream_t stream) {
  (void)in_sizes; (void)n_in; (void)out_size; (void)ws_size;
  const float* hidden  = (const float*)d_in[0];
  const float* wq      = (const float*)d_in[2];
  const float* wk      = (const float*)d_in[3];
  const float* wv      = (const float*)d_in[4];
  const float* wo      = (const float*)d_in[5];
  const float* q_scale = (const float*)d_in[6];
  const float* k_scale = (const float*)d_in[7];
  float* out = (float*)d_out;

  uint8_t* ws = (uint8_t*)d_ws;
  _Float16* hid_h = (_Float16*)ws;  ws += (size_t)MR * HID * 2;        // 16.78MB
  _Float16* Wt    = (_Float16*)ws;  ws += (size_t)3072 * HID * 2;      // 12.58MB (QKV^T; reused for wo^T)
  float*    QKVp  = (float*)ws;     ws += (size_t)MR * 3072 * 4;       // 50.33MB (reused as Ah)
  _Float16* Qh    = (_Float16*)ws;  ws += (size_t)MR * HID * 2;        // 16.78MB
  _Float16* Kh    = (_Float16*)ws;  ws += (size_t)MR * 512 * 2;        // 4.19MB
  _Float16* Vh    = (_Float16*)ws;  ws += (size_t)MR * 512 * 2;        // 4.19MB
  _Float16* Vt    = (_Float16*)ws;  ws += (size_t)MR * 512 * 2;        // 4.19MB
  _Float16* Ah    = (_Float16*)QKVp;  // overlay (QKVp dead after norms)

  const dim3 blk(256);
  cvt_f16<<<dim3(8192), blk, 0, stream>>>(hidden, hid_h, MR * HID / 4);
  wtrans<<<dim3(64, 64), blk, 0, stream>>>(wq, Wt, 2048, 2048);
  wtrans<<<dim3(16, 64), blk, 0, stream>>>(wk, Wt + (size_t)2048 * 2048, 512, 2048);
  wtrans<<<dim3(16, 64), blk, 0, stream>>>(wv, Wt + (size_t)2560 * 2048, 512, 2048);
  // fused QKV projection: [4096,2048] @ [2048,3072]
  gemm_f16<<<dim3(24, 32), blk, 0, stream>>>(hid_h, Wt, QKVp, 3072, 2048);
  // Wt is free now -> wo^T
  wtrans<<<dim3(64, 64), blk, 0, stream>>>(wo, Wt, 2048, 2048);
  norm_rope_q<<<dim3(32768), blk, 0, stream>>>(QKVp, Qh, q_scale);
  norm_kv<<<dim3(16384), blk, 0, stream>>>(QKVp, Kh, Vh, k_scale);
  transpose_v<<<dim3(64, 8, 4), blk, 0, stream>>>(Vh, Vt);
  attn_f16<<<dim3(32, 8, 2), blk, 0, stream>>>(Qh, Kh, Vt, Ah);
  gemm_f16<<<dim3(16, 32), blk, 0, stream>>>(Ah, Wt, out, 2048, 2048);
}